// Round 19
// baseline (522.965 us; speedup 1.0000x reference)
//
#include <hip/hip_runtime.h>
#include <math.h>

#define B_ 1024
#define N_ 64
#define F_ 512

typedef const __attribute__((address_space(1))) float* gptr_t;
typedef __attribute__((address_space(3))) float* lptr_t;
typedef _Float16 half_t;
typedef half_t half8 __attribute__((ext_vector_type(8)));
typedef half_t half4 __attribute__((ext_vector_type(4)));
typedef float f32x4 __attribute__((ext_vector_type(4)));

__device__ __forceinline__ void gload16(const float* g, float* l) {
  __builtin_amdgcn_global_load_lds((gptr_t)g, (lptr_t)l, 16, 0, 0);
}

// swizzled LDS addresses (halves): octet-XOR keeps b128 frag reads 2-way max
#define XMI(n, f) ((n) * 128 + (((((f) >> 3) ^ ((n) >> 0 & 7))) << 3) + ((f) & 7))
#define SQI(n, m) ((n) * 64 + (((((m) >> 3) ^ ((n) & 7))) << 3) + ((m) & 7))

#define MFMA3(accv, ah, al, bh, bl)                                           \
  do {                                                                        \
    accv = __builtin_amdgcn_mfma_f32_16x16x32_f16(ah, bh, accv, 0, 0, 0);     \
    accv = __builtin_amdgcn_mfma_f32_16x16x32_f16(ah, bl, accv, 0, 0, 0);     \
    accv = __builtin_amdgcn_mfma_f32_16x16x32_f16(al, bh, accv, 0, 0, 0);     \
  } while (0)

// ---------------------------------------------------------------------------
// Kernel 0: pre-split W (x512) into f16 hi/lo, transposed + swizzled.
// ---------------------------------------------------------------------------
__global__ __launch_bounds__(256) void k_split_w(const float* __restrict__ W,
                                                 half_t* __restrict__ wt_hi,
                                                 half_t* __restrict__ wt_lo) {
  int idx = blockIdx.x * 256 + threadIdx.x;  // 0..262143
  int k = idx >> 9, n = idx & 511;
  float wv = W[idx] * 512.0f;
  half_t hh = (half_t)wv;
  half_t hl = (half_t)(wv - (float)hh);
  int f = (n ^ (n >> 1)) & 3;
  int pos = ((k >> 3) & 3) ^ f;
  int addr = n * 512 + (k & ~31) + (pos << 3) + (k & 7);
  wt_hi[addr] = hh;
  wt_lo[addr] = hl;
}

// ---------------------------------------------------------------------------
// Kernel 1 v8: A never touches LDS. Each lane global-loads its own A-frag
// rows (L1-resident 16-row x 128B step window), splits in-reg; only B is
// LDS-staged (double-buffered, 32KB total -> 4 blocks/CU). ONE barrier per
// K-step with counted vmcnt(8): stage of the idle B buffer is issued AFTER
// the barrier (all waves' previous MFMA reads retired -> no overwrite race);
// A-loads stay in flight across the barrier. Math bit-identical.
// ---------------------------------------------------------------------------
__global__ __launch_bounds__(256, 4) void k_wh(const float* __restrict__ hA,
                                               const half_t* __restrict__ WTh,
                                               const half_t* __restrict__ WTl,
                                               float* __restrict__ Wh) {
  __shared__ half_t Bh[2][128 * 32];   // 8KB x2
  __shared__ half_t Bl[2][128 * 32];   // 8KB x2   -> 32KB total

  const int bid = blockIdx.x;                    // 0..2047
  const int wg  = (bid & 7) * 256 + (bid >> 3);  // XCD-grouped (2048%8==0)
  const int mt  = wg >> 2;                       // M-tile 0..511
  const int nt  = wg & 3;                        // N-tile 0..3
  const int t = threadIdx.x;
  const int w = t >> 6, lane = t & 63;
  const int wr = w >> 1, wc = w & 1;             // wave 64x64 sub-tile
  const int lr = lane & 15, ko = lane >> 4;

  const float* Ab = hA + (size_t)mt * 128 * F_;
  const int n0 = nt * 128;

  // per-lane A row bases (4 frags)
  const float* Arow[4];
#pragma unroll
  for (int i = 0; i < 4; ++i)
    Arow[i] = Ab + (size_t)(wr * 64 + i * 16 + lr) * F_ + ko * 8;

  // B staging from pre-split tables: 2 slots/thread/plane.
  int Bsrc[2], Blds[2];
#pragma unroll
  for (int i = 0; i < 2; ++i) {
    int s = t + 256 * i;
    int n = s >> 2, sl = s & 3;
    Bsrc[i] = (n0 + n) * 512 + sl * 8;
    Blds[i] = s * 8;
  }

  f32x4 acc[4][4];
#pragma unroll
  for (int i = 0; i < 4; ++i)
#pragma unroll
    for (int j = 0; j < 4; ++j) acc[i][j] = (f32x4){0.f, 0.f, 0.f, 0.f};

  float4 areg[4][2];

#define LOADA(k0)                                                            \
  do {                                                                       \
    _Pragma("unroll") for (int i_ = 0; i_ < 4; ++i_) {                       \
      areg[i_][0] = *(const float4*)(Arow[i_] + (k0));                       \
      areg[i_][1] = *(const float4*)(Arow[i_] + (k0) + 4);                   \
    }                                                                        \
  } while (0)

#define STAGE_B(buf, k0)                                                     \
  do {                                                                       \
    _Pragma("unroll") for (int i_ = 0; i_ < 2; ++i_)                         \
        gload16((const float*)(WTh + (size_t)(k0) + Bsrc[i_]),               \
                (float*)&Bh[buf][Blds[i_]]);                                 \
    _Pragma("unroll") for (int i_ = 0; i_ < 2; ++i_)                         \
        gload16((const float*)(WTl + (size_t)(k0) + Bsrc[i_]),               \
                (float*)&Bl[buf][Blds[i_]]);                                 \
  } while (0)

  LOADA(0);
  STAGE_B(0, 0);
  __syncthreads();   // one-time full drain (A(0) + B(0) landed everywhere)

#pragma unroll 1
  for (int kt = 0; kt < 16; ++kt) {
    const int cur = kt & 1;

    // barrier (kt>0): retire previous step's 4 B-gloads (oldest in FIFO;
    // own A-loads, 8 ops, stay in flight). Arrival implies every wave's
    // previous MFMA ds_reads retired -> idle buffer safe to overwrite.
    if (kt > 0) {
      asm volatile("s_waitcnt vmcnt(8)" ::: "memory");
      __builtin_amdgcn_sched_barrier(0);
      __builtin_amdgcn_s_barrier();
      __builtin_amdgcn_sched_barrier(0);
    }

    // stage next B tile into the idle buffer (safe after barrier).
    if (kt < 15) STAGE_B(cur ^ 1, (kt + 1) * 32);

    // split this step's A (compiler waits the areg vm deps).
    half8 ah[4], al[4];
#pragma unroll
    for (int i = 0; i < 4; ++i) {
#pragma unroll
      for (int q = 0; q < 4; ++q) {
        float xs = ((const float*)&areg[i][0])[q] * 16.0f;
        half_t h = (half_t)xs;
        ah[i][q] = h;
        al[i][q] = (half_t)(xs - (float)h);
      }
#pragma unroll
      for (int q = 0; q < 4; ++q) {
        float xs = ((const float*)&areg[i][1])[q] * 16.0f;
        half_t h = (half_t)xs;
        ah[i][4 + q] = h;
        al[i][4 + q] = (half_t)(xs - (float)h);
      }
    }

    // MFMA cluster (B[cur] landed: counted wait + barrier above).
    __builtin_amdgcn_s_setprio(1);
#pragma unroll
    for (int j = 0; j < 4; ++j) {
      int nb = wc * 64 + j * 16 + lr;
      int p = ko ^ ((nb ^ (nb >> 1)) & 3);
      half8 bh = *(const half8*)&Bh[cur][nb * 32 + p * 8];
      half8 bl = *(const half8*)&Bl[cur][nb * 32 + p * 8];
#pragma unroll
      for (int i = 0; i < 4; ++i) MFMA3(acc[i][j], ah[i], al[i], bh, bl);
    }
    __builtin_amdgcn_s_setprio(0);

    // issue next step's A loads (latency hides across the next barrier).
    if (kt < 15) LOADA((kt + 1) * 32);
  }

  const float sc = 1.0f / 8192.0f;
  float* whb = Wh + ((size_t)mt * 128 + wr * 64) * F_ + n0 + wc * 64;
#pragma unroll
  for (int i = 0; i < 4; ++i) {
#pragma unroll
    for (int rr = 0; rr < 4; ++rr) {
      int row = i * 16 + ko * 4 + rr;
#pragma unroll
      for (int j = 0; j < 4; ++j)
        whb[row * F_ + j * 16 + lr] = acc[i][j][rr] * sc;
    }
  }
#undef LOADA
#undef STAGE_B
}

// ---------------------------------------------------------------------------
// Kernel 2: r18 k_attn verbatim (passing, Gram + T14).
// ---------------------------------------------------------------------------
__global__ __launch_bounds__(256) void k_attn(const float* __restrict__ Wh,
                                              const float* __restrict__ A1,
                                              const float* __restrict__ A2,
                                              const float* __restrict__ betap,
                                              float* __restrict__ out) {
  __shared__ float sm[12416];
  half_t* e_h   = (half_t*)sm;
  half_t* e_l   = e_h + 4096;
  half_t* xm_h  = (half_t*)(sm + 4096);
  half_t* xm_l  = xm_h + 8192;
  half_t* hid_h = (half_t*)(sm + 4096);
  half_t* hid_l = (half_t*)(sm + 6144);
  half_t* ab_h  = (half_t*)(sm + 8192);
  half_t* ab_l  = (half_t*)(sm + 10240);
  half_t* at_h  = (half_t*)sm;
  half_t* at_l  = at_h + 4096;
  half_t* wt_h  = (half_t*)(sm + 4096);
  half_t* wt_l  = (half_t*)(sm + 8192);
  float* mu  = sm + 12288;   // row SUMS (raw units)
  float* nrm = sm + 12352;

  const int b = blockIdx.x;
  const int t = threadIdx.x;
  const int w = t >> 6, lane = t & 63;
  const int lr = lane & 15, ko = lane >> 4;
  const float beta = betap[0];
  const float* whb = Wh + (size_t)b * N_ * F_;

  float4 vbuf[8];
#define LOAD_XM(c_)                                                           \
  do {                                                                        \
    _Pragma("unroll") for (int i_ = 0; i_ < 8; ++i_) {                        \
      int id_ = t + 256 * i_;                                                 \
      int n_ = id_ >> 5, c4_ = id_ & 31;                                      \
      vbuf[i_] = *(const float4*)(whb + n_ * F_ + (c_) * 128 + c4_ * 4);      \
    }                                                                         \
  } while (0)

  if (t < 64) mu[t] = 0.f;
  LOAD_XM(0);
  __syncthreads();

  // ---- phase 2: Gram = X @ X^T via MFMA (raw x16), row sums folded ----
  f32x4 covA[4];
#pragma unroll
  for (int j = 0; j < 4; ++j) covA[j] = (f32x4){0.f, 0.f, 0.f, 0.f};

#pragma unroll 1
  for (int c = 0; c < 4; ++c) {
#pragma unroll
    for (int i = 0; i < 8; ++i) {
      int id = t + 256 * i;
      int n = id >> 5, c4 = id & 31;
      float4 v = vbuf[i];
      float s4 = v.x + v.y + v.z + v.w;
      float x0 = v.x * 16.f, x1 = v.y * 16.f;
      float x2 = v.z * 16.f, x3 = v.w * 16.f;
      half4 hh, hl;
      hh[0] = (half_t)x0; hl[0] = (half_t)(x0 - (float)hh[0]);
      hh[1] = (half_t)x1; hl[1] = (half_t)(x1 - (float)hh[1]);
      hh[2] = (half_t)x2; hl[2] = (half_t)(x2 - (float)hh[2]);
      hh[3] = (half_t)x3; hl[3] = (half_t)(x3 - (float)hh[3]);
      int ad = n * 128 + (((c4 >> 1) ^ (n & 7)) << 3) + (c4 & 1) * 4;
      *(half4*)&xm_h[ad] = hh;
      *(half4*)&xm_l[ad] = hl;
      s4 += __shfl_xor(s4, 1);
      s4 += __shfl_xor(s4, 2);
      s4 += __shfl_xor(s4, 4);
      s4 += __shfl_xor(s4, 8);
      s4 += __shfl_xor(s4, 16);
      if ((lane & 31) == 0) mu[n] += s4;
    }
    __syncthreads();
    if (c < 3) LOAD_XM(c + 1);
#pragma unroll
    for (int s = 0; s < 4; ++s) {
      int ra = w * 16 + lr;
      half8 ah = *(const half8*)&xm_h[XMI(ra, (s * 4 + ko) * 8)];
      half8 al = *(const half8*)&xm_l[XMI(ra, (s * 4 + ko) * 8)];
#pragma unroll
      for (int j = 0; j < 4; ++j) {
        int rb = j * 16 + lr;
        half8 bh = *(const half8*)&xm_h[XMI(rb, (s * 4 + ko) * 8)];
        half8 bl = *(const half8*)&xm_l[XMI(rb, (s * 4 + ko) * 8)];
        covA[j] = __builtin_amdgcn_mfma_f32_16x16x32_f16(ah, bh, covA[j], 0, 0, 0);
        covA[j] = __builtin_amdgcn_mfma_f32_16x16x32_f16(ah, bl, covA[j], 0, 0, 0);
        covA[j] = __builtin_amdgcn_mfma_f32_16x16x32_f16(al, bh, covA[j], 0, 0, 0);
      }
    }
    __syncthreads();
  }
#undef LOAD_XM

  // ---- phase 3: Gram -> cov, norms ----
  {
    float sn[4], smv[4];
#pragma unroll
    for (int r = 0; r < 4; ++r) sn[r] = mu[w * 16 + 4 * ko + r];
#pragma unroll
    for (int j = 0; j < 4; ++j) smv[j] = mu[j * 16 + lr];
#pragma unroll
    for (int j = 0; j < 4; ++j)
#pragma unroll
      for (int r = 0; r < 4; ++r) covA[j][r] -= 0.5f * sn[r] * smv[j];
  }
#pragma unroll
  for (int r = 0; r < 4; ++r)
    if (lr == 4 * ko + r) nrm[w * 16 + lr] = sqrtf(fmaxf(covA[w][r], 0.f));
  __syncthreads();

  // ---- phase 4: e = beta*|corr| + split to LDS ----
  float e32[4][4];
#pragma unroll
  for (int j = 0; j < 4; ++j) {
#pragma unroll
    for (int r = 0; r < 4; ++r) {
      int n = w * 16 + 4 * ko + r;
      int m = j * 16 + lr;
      float denom = nrm[n] * nrm[m] + 2.56e-6f;
      float e = beta * fabsf(covA[j][r] / denom);
      e32[j][r] = e;
      float es = e * 16.f;
      half_t hh = (half_t)es;
      e_h[SQI(n, m)] = hh;
      e_l[SQI(n, m)] = (half_t)(es - (float)hh);
    }
  }

  // ---- phase 5: MLP via MFMA, K-chunked, T14-prefetched ----
  float a1buf[16], a2buf[16];
#define LOAD_A1(jc_)                                                          \
  do {                                                                        \
    _Pragma("unroll") for (int hf_ = 0; hf_ < 2; ++hf_)                       \
      _Pragma("unroll") for (int q_ = 0; q_ < 8; ++q_)                        \
        a1buf[hf_ * 8 + q_] =                                                 \
            A1[(size_t)((w + 4 * hf_) * 8 + q_) * 256 + (jc_) * 64 + lane];   \
  } while (0)
#define LOAD_A2(jc_)                                                          \
  do {                                                                        \
    _Pragma("unroll") for (int hf_ = 0; hf_ < 2; ++hf_)                       \
      _Pragma("unroll") for (int q_ = 0; q_ < 8; ++q_)                        \
        a2buf[hf_ * 8 + q_] =                                                 \
            A2[(size_t)((jc_) * 64 + (w + 4 * hf_) * 8 + q_) * 64 + lane];    \
  } while (0)

  LOAD_A1(0);
  __syncthreads();

  f32x4 adj[4];
#pragma unroll
  for (int j = 0; j < 4; ++j) adj[j] = (f32x4){0.f, 0.f, 0.f, 0.f};

#pragma unroll 1
  for (int jc = 0; jc < 4; ++jc) {
#pragma unroll
    for (int hf = 0; hf < 2; ++hf) {
      int mo = w + 4 * hf;
      int jl = lane;
      half8 hh, hl;
#pragma unroll
      for (int q = 0; q < 8; ++q) {
        float x = a1buf[hf * 8 + q] * 64.f;
        half_t h = (half_t)x;
        hh[q] = h; hl[q] = (half_t)(x - (float)h);
      }
      int ad = jl * 64 + ((mo ^ (jl & 7)) << 3);
      *(half8*)&ab_h[ad] = hh;
      *(half8*)&ab_l[ad] = hl;
    }
    __syncthreads();
    LOAD_A2(jc);

    f32x4 h1[4];
#pragma unroll
    for (int j = 0; j < 4; ++j) h1[j] = (f32x4){0.f, 0.f, 0.f, 0.f};
#pragma unroll
    for (int s = 0; s < 2; ++s) {
      int ra = w * 16 + lr;
      half8 ah = *(const half8*)&e_h[SQI(ra, (s * 4 + ko) * 8)];
      half8 al = *(const half8*)&e_l[SQI(ra, (s * 4 + ko) * 8)];
#pragma unroll
      for (int jt = 0; jt < 4; ++jt) {
        int jl = jt * 16 + lr;
        half8 bh = *(const half8*)&ab_h[SQI(jl, (s * 4 + ko) * 8)];
        half8 bl = *(const half8*)&ab_l[SQI(jl, (s * 4 + ko) * 8)];
        h1[jt] = __builtin_amdgcn_mfma_f32_16x16x32_f16(ah, bh, h1[jt], 0, 0, 0);
        h1[jt] = __builtin_amdgcn_mfma_f32_16x16x32_f16(ah, bl, h1[jt], 0, 0, 0);
        h1[jt] = __builtin_amdgcn_mfma_f32_16x16x32_f16(al, bh, h1[jt], 0, 0, 0);
      }
    }
#pragma unroll
    for (int jt = 0; jt < 4; ++jt) {
#pragma unroll
      for (int r = 0; r < 4; ++r) {
        float x = fmaxf(h1[jt][r], 0.f);
        int n = w * 16 + 4 * ko + r;
        int jl = jt * 16 + lr;
        half_t hh = (half_t)x;
        hid_h[SQI(n, jl)] = hh;
        hid_l[SQI(n, jl)] = (half_t)(x - (float)hh);
      }
    }
    __syncthreads();

#pragma unroll
    for (int hf = 0; hf < 2; ++hf) {
      int ko2 = w + 4 * hf;
      int m = lane;
      half8 hh, hl;
#pragma unroll
      for (int q = 0; q < 8; ++q) {
        float x = a2buf[hf * 8 + q] * 64.f;
        half_t h = (half_t)x;
        hh[q] = h; hl[q] = (half_t)(x - (float)h);
      }
      int ad = m * 64 + ((ko2 ^ (m & 7)) << 3);
      *(half8*)&ab_h[ad] = hh;
      *(half8*)&ab_l[ad] = hl;
    }
    __syncthreads();
    if (jc < 3) LOAD_A1(jc + 1);

#pragma unroll
    for (int s = 0; s < 2; ++s) {
      int ra = w * 16 + lr;
      half8 ah = *(const half8*)&hid_h[SQI(ra, (s * 4 + ko) * 8)];
      half8 al = *(const half8*)&hid_l[SQI(ra, (s * 4 + ko) * 8)];
#pragma unroll
      for (int mt = 0; mt < 4; ++mt) {
        int m = mt * 16 + lr;
        half8 bh = *(const half8*)&ab_h[SQI(m, (s * 4 + ko) * 8)];
        half8 bl = *(const half8*)&ab_l[SQI(m, (s * 4 + ko) * 8)];
        adj[mt] = __builtin_amdgcn_mfma_f32_16x16x32_f16(ah, bh, adj[mt], 0, 0, 0);
        adj[mt] = __builtin_amdgcn_mfma_f32_16x16x32_f16(ah, bl, adj[mt], 0, 0, 0);
        adj[mt] = __builtin_amdgcn_mfma_f32_16x16x32_f16(al, bh, adj[mt], 0, 0, 0);
      }
    }
    __syncthreads();
  }
#undef LOAD_A1
#undef LOAD_A2

  // ---- phase 6: mask + row-softmax, split probs -> at_hl ----
  {
    float p[4][4];
#pragma unroll
    for (int r = 0; r < 4; ++r) {
      float mx = -3.0e38f;
#pragma unroll
      for (int mt = 0; mt < 4; ++mt) {
        float pre = e32[mt][r] + adj[mt][r] * (1.f / 65536.f);
        p[mt][r] = (pre > 0.f) ? e32[mt][r] : -1e12f;
        mx = fmaxf(mx, p[mt][r]);
      }
      mx = fmaxf(mx, __shfl_xor(mx, 1));
      mx = fmaxf(mx, __shfl_xor(mx, 2));
      mx = fmaxf(mx, __shfl_xor(mx, 4));
      mx = fmaxf(mx, __shfl_xor(mx, 8));
      float ssum = 0.f;
#pragma unroll
      for (int mt = 0; mt < 4; ++mt) {
        p[mt][r] = expf(p[mt][r] - mx);
        ssum += p[mt][r];
      }
      ssum += __shfl_xor(ssum, 1);
      ssum += __shfl_xor(ssum, 2);
      ssum += __shfl_xor(ssum, 4);
      ssum += __shfl_xor(ssum, 8);
      float inv = 1.f / ssum;
      int n = w * 16 + 4 * ko + r;
#pragma unroll
      for (int mt = 0; mt < 4; ++mt) {
        float pv = p[mt][r] * inv;
        int m = mt * 16 + lr;
        half_t hh = (half_t)pv;
        at_h[SQI(n, m)] = hh;
        at_l[SQI(n, m)] = (half_t)(pv - (float)hh);
      }
    }
  }

  // ---- phase 7: out = attn @ Wh via MFMA, T14-prefetched chunks ----
  const int fl0 = t & 127;
  const int moB = t >> 7;
  float wbuf[32];
#define LOAD_WT(fc_)                                                          \
  do {                                                                        \
    _Pragma("unroll") for (int i_ = 0; i_ < 4; ++i_) {                        \
      int mo_ = moB + 2 * i_;                                                 \
      _Pragma("unroll") for (int q_ = 0; q_ < 8; ++q_)                        \
        wbuf[i_ * 8 + q_] =                                                   \
            whb[(size_t)(mo_ * 8 + q_) * F_ + (fc_) * 128 + fl0];             \
    }                                                                         \
  } while (0)

  LOAD_WT(0);
#pragma unroll 1
  for (int fc = 0; fc < 4; ++fc) {
    __syncthreads();
#pragma unroll
    for (int i = 0; i < 4; ++i) {
      int mo = moB + 2 * i;
      half8 hh, hl;
#pragma unroll
      for (int q = 0; q < 8; ++q) {
        float x = wbuf[i * 8 + q];
        half_t h = (half_t)x;
        hh[q] = h; hl[q] = (half_t)(x - (float)h);
      }
      int ad = fl0 * 64 + ((mo ^ (fl0 & 7)) << 3);
      *(half8*)&wt_h[ad] = hh;
      *(half8*)&wt_l[ad] = hl;
    }
    __syncthreads();
    if (fc < 3) LOAD_WT(fc + 1);

    half8 aah[2], aal[2];
#pragma unroll
    for (int s = 0; s < 2; ++s) {
      int n = w * 16 + lr;
      aah[s] = *(const half8*)&at_h[SQI(n, (s * 4 + ko) * 8)];
      aal[s] = *(const half8*)&at_l[SQI(n, (s * 4 + ko) * 8)];
    }
#pragma unroll
    for (int ft = 0; ft < 8; ++ft) {
      f32x4 po = (f32x4){0.f, 0.f, 0.f, 0.f};
#pragma unroll
      for (int s = 0; s < 2; ++s) {
        int fl = ft * 16 + lr;
        int ad = fl * 64 + (((((s * 4 + ko)) ^ (fl & 7))) << 3);
        half8 bh = *(const half8*)&wt_h[ad];
        half8 bl = *(const half8*)&wt_l[ad];
        po = __builtin_amdgcn_mfma_f32_16x16x32_f16(aah[s], bh, po, 0, 0, 0);
        po = __builtin_amdgcn_mfma_f32_16x16x32_f16(aah[s], bl, po, 0, 0, 0);
        po = __builtin_amdgcn_mfma_f32_16x16x32_f16(aal[s], bh, po, 0, 0, 0);
      }
      int fg = fc * 128 + ft * 16 + lr;
#pragma unroll
      for (int r = 0; r < 4; ++r) {
        int n = w * 16 + 4 * ko + r;
        out[(size_t)b * N_ * F_ + n * F_ + fg] = po[r];
      }
    }
  }
#undef LOAD_WT
}

extern "C" void kernel_launch(void* const* d_in, const int* in_sizes, int n_in,
                              void* d_out, int out_size, void* d_ws, size_t ws_size,
                              hipStream_t stream) {
  const float* h    = (const float*)d_in[0];
  const float* W    = (const float*)d_in[1];
  const float* beta = (const float*)d_in[2];
  const float* A1   = (const float*)d_in[3];
  const float* A2   = (const float*)d_in[4];
  float* out = (float*)d_out;
  float* Wh  = (float*)d_ws;  // 128 MiB workspace

  half_t* wt_hi = (half_t*)d_out;
  half_t* wt_lo = wt_hi + 512 * 512;

  k_split_w<<<1024, 256, 0, stream>>>(W, wt_hi, wt_lo);
  k_wh<<<2048, 256, 0, stream>>>(h, wt_hi, wt_lo, Wh);
  k_attn<<<B_, 256, 0, stream>>>(Wh, A1, A2, beta, out);
}

// Round 20
// 220.573 us; speedup vs baseline: 2.3709x; 2.3709x over previous
//
#include <hip/hip_runtime.h>
#include <math.h>

#define B_ 1024
#define N_ 64
#define F_ 512

typedef const __attribute__((address_space(1))) float* gptr_t;
typedef __attribute__((address_space(3))) float* lptr_t;
typedef _Float16 half_t;
typedef half_t half8 __attribute__((ext_vector_type(8)));
typedef half_t half4 __attribute__((ext_vector_type(4)));
typedef float f32x4 __attribute__((ext_vector_type(4)));

__device__ __forceinline__ void gload16(const float* g, float* l) {
  __builtin_amdgcn_global_load_lds((gptr_t)g, (lptr_t)l, 16, 0, 0);
}

// swizzled LDS addresses (halves): octet-XOR keeps b128 frag reads 2-way max
#define XMI(n, f) ((n) * 128 + (((((f) >> 3) ^ ((n) >> 0 & 7))) << 3) + ((f) & 7))
#define SQI(n, m) ((n) * 64 + (((((m) >> 3) ^ ((n) & 7))) << 3) + ((m) & 7))

#define MFMA3(accv, ah, al, bh, bl)                                           \
  do {                                                                        \
    accv = __builtin_amdgcn_mfma_f32_16x16x32_f16(ah, bh, accv, 0, 0, 0);     \
    accv = __builtin_amdgcn_mfma_f32_16x16x32_f16(ah, bl, accv, 0, 0, 0);     \
    accv = __builtin_amdgcn_mfma_f32_16x16x32_f16(al, bh, accv, 0, 0, 0);     \
  } while (0)

// ---------------------------------------------------------------------------
// Kernel 0: pre-split W (x512) into f16 hi/lo, transposed + swizzled.
// ---------------------------------------------------------------------------
__global__ __launch_bounds__(256) void k_split_w(const float* __restrict__ W,
                                                 half_t* __restrict__ wt_hi,
                                                 half_t* __restrict__ wt_lo) {
  int idx = blockIdx.x * 256 + threadIdx.x;  // 0..262143
  int k = idx >> 9, n = idx & 511;
  float wv = W[idx] * 512.0f;
  half_t hh = (half_t)wv;
  half_t hl = (half_t)(wv - (float)hh);
  int f = (n ^ (n >> 1)) & 3;
  int pos = ((k >> 3) & 3) ^ f;
  int addr = n * 512 + (k & ~31) + (pos << 3) + (k & 7);
  wt_hi[addr] = hh;
  wt_lo[addr] = hl;
}

// ---------------------------------------------------------------------------
// Kernel 1 v7 (r17/r18, best measured): 128x128 tile, 48KB LDS, 3 blocks/CU,
// A pre-split at staging (single-buffered hi/lo), B double-buffered via
// gload16, counted-vmcnt + setprio.
// ---------------------------------------------------------------------------
__global__ __launch_bounds__(256, 3) void k_wh(const float* __restrict__ hA,
                                               const half_t* __restrict__ WTh,
                                               const half_t* __restrict__ WTl,
                                               float* __restrict__ Wh) {
  __shared__ half_t Ah[128 * 32];      // 8KB, single buffer
  __shared__ half_t Alo[128 * 32];     // 8KB
  __shared__ half_t Bh[2][128 * 32];   // 8KB x2
  __shared__ half_t Bl[2][128 * 32];   // 8KB x2   -> 48KB total

  const int bid = blockIdx.x;                    // 0..2047
  const int wg  = (bid & 7) * 256 + (bid >> 3);  // XCD-grouped (2048%8==0)
  const int mt  = wg >> 2;                       // M-tile 0..511
  const int nt  = wg & 3;                        // N-tile 0..3
  const int t = threadIdx.x;
  const int w = t >> 6, lane = t & 63;
  const int wr = w >> 1, wc = w & 1;             // wave 64x64 sub-tile
  const int lr = lane & 15, ko = lane >> 4;

  const float* Ab = hA + (size_t)mt * 128 * F_;
  const int n0 = nt * 128;

  int Arow[2], Aoct[2], Aad[2];
#pragma unroll
  for (int i = 0; i < 2; ++i) {
    int id = t + 256 * i;
    int row = id >> 2, oct = id & 3;
    Arow[i] = row;
    Aoct[i] = oct;
    Aad[i] = row * 32 + ((oct ^ ((row ^ (row >> 1)) & 3)) << 3);
  }
  int Bsrc[2], Blds[2];
#pragma unroll
  for (int i = 0; i < 2; ++i) {
    int s = t + 256 * i;
    int n = s >> 2, sl = s & 3;
    Bsrc[i] = (n0 + n) * 512 + sl * 8;
    Blds[i] = s * 8;
  }

  f32x4 acc[4][4];
#pragma unroll
  for (int i = 0; i < 4; ++i)
#pragma unroll
    for (int j = 0; j < 4; ++j) acc[i][j] = (f32x4){0.f, 0.f, 0.f, 0.f};

  float4 areg[2][2];

#define LOADA(k0)                                                            \
  do {                                                                       \
    _Pragma("unroll") for (int i_ = 0; i_ < 2; ++i_) {                       \
      const float* p = Ab + (size_t)Arow[i_] * F_ + (k0) + Aoct[i_] * 8;     \
      areg[i_][0] = *(const float4*)p;                                       \
      areg[i_][1] = *(const float4*)(p + 4);                                 \
    }                                                                        \
  } while (0)

#define WRITEA()                                                             \
  do {                                                                       \
    _Pragma("unroll") for (int i_ = 0; i_ < 2; ++i_) {                       \
      half8 hh, hl;                                                          \
      _Pragma("unroll") for (int q = 0; q < 4; ++q) {                        \
        float xs = ((const float*)&areg[i_][0])[q] * 16.0f;                  \
        half_t h = (half_t)xs;                                               \
        hh[q] = h; hl[q] = (half_t)(xs - (float)h);                          \
      }                                                                      \
      _Pragma("unroll") for (int q = 0; q < 4; ++q) {                        \
        float xs = ((const float*)&areg[i_][1])[q] * 16.0f;                  \
        half_t h = (half_t)xs;                                               \
        hh[4 + q] = h; hl[4 + q] = (half_t)(xs - (float)h);                  \
      }                                                                      \
      *(half8*)&Ah[Aad[i_]] = hh;                                            \
      *(half8*)&Alo[Aad[i_]] = hl;                                           \
    }                                                                        \
  } while (0)

#define STAGE_B(buf, k0)                                                     \
  do {                                                                       \
    _Pragma("unroll") for (int i_ = 0; i_ < 2; ++i_)                         \
        gload16((const float*)(WTh + (size_t)(k0) + Bsrc[i_]),               \
                (float*)&Bh[buf][Blds[i_]]);                                 \
    _Pragma("unroll") for (int i_ = 0; i_ < 2; ++i_)                         \
        gload16((const float*)(WTl + (size_t)(k0) + Bsrc[i_]),               \
                (float*)&Bl[buf][Blds[i_]]);                                 \
  } while (0)

  LOADA(0);
  STAGE_B(0, 0);
  WRITEA();
  __syncthreads();

#pragma unroll 1
  for (int kt = 0; kt < 16; ++kt) {
    const int cur = kt & 1;
    if (kt < 15) {
      LOADA((kt + 1) * 32);
      STAGE_B(cur ^ 1, (kt + 1) * 32);
    }

    half8 ah[4], al[4];
#pragma unroll
    for (int i = 0; i < 4; ++i) {
      int r = wr * 64 + i * 16 + lr;
      int pa = r * 32 + ((ko ^ ((r ^ (r >> 1)) & 3)) << 3);
      ah[i] = *(const half8*)&Ah[pa];
      al[i] = *(const half8*)&Alo[pa];
    }

    if (kt < 15)
      asm volatile("s_waitcnt lgkmcnt(0) vmcnt(8)" ::: "memory");
    else
      asm volatile("s_waitcnt lgkmcnt(0) vmcnt(0)" ::: "memory");
    __builtin_amdgcn_sched_barrier(0);
    __builtin_amdgcn_s_barrier();
    __builtin_amdgcn_sched_barrier(0);

    if (kt < 15) WRITEA();

    __builtin_amdgcn_s_setprio(1);
#pragma unroll
    for (int j = 0; j < 4; ++j) {
      int nb = wc * 64 + j * 16 + lr;
      int p = ko ^ ((nb ^ (nb >> 1)) & 3);
      half8 bh = *(const half8*)&Bh[cur][nb * 32 + p * 8];
      half8 bl = *(const half8*)&Bl[cur][nb * 32 + p * 8];
#pragma unroll
      for (int i = 0; i < 4; ++i) MFMA3(acc[i][j], ah[i], al[i], bh, bl);
    }
    __builtin_amdgcn_s_setprio(0);

    asm volatile("s_waitcnt lgkmcnt(0)" ::: "memory");
    __builtin_amdgcn_sched_barrier(0);
    __builtin_amdgcn_s_barrier();
    __builtin_amdgcn_sched_barrier(0);
  }

  const float sc = 1.0f / 8192.0f;
  float* whb = Wh + ((size_t)mt * 128 + wr * 64) * F_ + n0 + wc * 64;
#pragma unroll
  for (int i = 0; i < 4; ++i) {
#pragma unroll
    for (int rr = 0; rr < 4; ++rr) {
      int row = i * 16 + ko * 4 + rr;
#pragma unroll
      for (int j = 0; j < 4; ++j)
        whb[row * F_ + j * 16 + lr] = acc[i][j][rr] * sc;
    }
  }
#undef LOADA
#undef WRITEA
#undef STAGE_B
}

// ---------------------------------------------------------------------------
// Kernel 2: r18 k_attn verbatim (passing, Gram + T14).
// ---------------------------------------------------------------------------
__global__ __launch_bounds__(256) void k_attn(const float* __restrict__ Wh,
                                              const float* __restrict__ A1,
                                              const float* __restrict__ A2,
                                              const float* __restrict__ betap,
                                              float* __restrict__ out) {
  __shared__ float sm[12416];
  half_t* e_h   = (half_t*)sm;
  half_t* e_l   = e_h + 4096;
  half_t* xm_h  = (half_t*)(sm + 4096);
  half_t* xm_l  = xm_h + 8192;
  half_t* hid_h = (half_t*)(sm + 4096);
  half_t* hid_l = (half_t*)(sm + 6144);
  half_t* ab_h  = (half_t*)(sm + 8192);
  half_t* ab_l  = (half_t*)(sm + 10240);
  half_t* at_h  = (half_t*)sm;
  half_t* at_l  = at_h + 4096;
  half_t* wt_h  = (half_t*)(sm + 4096);
  half_t* wt_l  = (half_t*)(sm + 8192);
  float* mu  = sm + 12288;   // row SUMS (raw units)
  float* nrm = sm + 12352;

  const int b = blockIdx.x;
  const int t = threadIdx.x;
  const int w = t >> 6, lane = t & 63;
  const int lr = lane & 15, ko = lane >> 4;
  const float beta = betap[0];
  const float* whb = Wh + (size_t)b * N_ * F_;

  float4 vbuf[8];
#define LOAD_XM(c_)                                                           \
  do {                                                                        \
    _Pragma("unroll") for (int i_ = 0; i_ < 8; ++i_) {                        \
      int id_ = t + 256 * i_;                                                 \
      int n_ = id_ >> 5, c4_ = id_ & 31;                                      \
      vbuf[i_] = *(const float4*)(whb + n_ * F_ + (c_) * 128 + c4_ * 4);      \
    }                                                                         \
  } while (0)

  if (t < 64) mu[t] = 0.f;
  LOAD_XM(0);
  __syncthreads();

  // ---- phase 2: Gram = X @ X^T via MFMA (raw x16), row sums folded ----
  f32x4 covA[4];
#pragma unroll
  for (int j = 0; j < 4; ++j) covA[j] = (f32x4){0.f, 0.f, 0.f, 0.f};

#pragma unroll 1
  for (int c = 0; c < 4; ++c) {
#pragma unroll
    for (int i = 0; i < 8; ++i) {
      int id = t + 256 * i;
      int n = id >> 5, c4 = id & 31;
      float4 v = vbuf[i];
      float s4 = v.x + v.y + v.z + v.w;
      float x0 = v.x * 16.f, x1 = v.y * 16.f;
      float x2 = v.z * 16.f, x3 = v.w * 16.f;
      half4 hh, hl;
      hh[0] = (half_t)x0; hl[0] = (half_t)(x0 - (float)hh[0]);
      hh[1] = (half_t)x1; hl[1] = (half_t)(x1 - (float)hh[1]);
      hh[2] = (half_t)x2; hl[2] = (half_t)(x2 - (float)hh[2]);
      hh[3] = (half_t)x3; hl[3] = (half_t)(x3 - (float)hh[3]);
      int ad = n * 128 + (((c4 >> 1) ^ (n & 7)) << 3) + (c4 & 1) * 4;
      *(half4*)&xm_h[ad] = hh;
      *(half4*)&xm_l[ad] = hl;
      s4 += __shfl_xor(s4, 1);
      s4 += __shfl_xor(s4, 2);
      s4 += __shfl_xor(s4, 4);
      s4 += __shfl_xor(s4, 8);
      s4 += __shfl_xor(s4, 16);
      if ((lane & 31) == 0) mu[n] += s4;
    }
    __syncthreads();
    if (c < 3) LOAD_XM(c + 1);
#pragma unroll
    for (int s = 0; s < 4; ++s) {
      int ra = w * 16 + lr;
      half8 ah = *(const half8*)&xm_h[XMI(ra, (s * 4 + ko) * 8)];
      half8 al = *(const half8*)&xm_l[XMI(ra, (s * 4 + ko) * 8)];
#pragma unroll
      for (int j = 0; j < 4; ++j) {
        int rb = j * 16 + lr;
        half8 bh = *(const half8*)&xm_h[XMI(rb, (s * 4 + ko) * 8)];
        half8 bl = *(const half8*)&xm_l[XMI(rb, (s * 4 + ko) * 8)];
        covA[j] = __builtin_amdgcn_mfma_f32_16x16x32_f16(ah, bh, covA[j], 0, 0, 0);
        covA[j] = __builtin_amdgcn_mfma_f32_16x16x32_f16(ah, bl, covA[j], 0, 0, 0);
        covA[j] = __builtin_amdgcn_mfma_f32_16x16x32_f16(al, bh, covA[j], 0, 0, 0);
      }
    }
    __syncthreads();
  }
#undef LOAD_XM

  // ---- phase 3: Gram -> cov, norms ----
  {
    float sn[4], smv[4];
#pragma unroll
    for (int r = 0; r < 4; ++r) sn[r] = mu[w * 16 + 4 * ko + r];
#pragma unroll
    for (int j = 0; j < 4; ++j) smv[j] = mu[j * 16 + lr];
#pragma unroll
    for (int j = 0; j < 4; ++j)
#pragma unroll
      for (int r = 0; r < 4; ++r) covA[j][r] -= 0.5f * sn[r] * smv[j];
  }
#pragma unroll
  for (int r = 0; r < 4; ++r)
    if (lr == 4 * ko + r) nrm[w * 16 + lr] = sqrtf(fmaxf(covA[w][r], 0.f));
  __syncthreads();

  // ---- phase 4: e = beta*|corr| + split to LDS ----
  float e32[4][4];
#pragma unroll
  for (int j = 0; j < 4; ++j) {
#pragma unroll
    for (int r = 0; r < 4; ++r) {
      int n = w * 16 + 4 * ko + r;
      int m = j * 16 + lr;
      float denom = nrm[n] * nrm[m] + 2.56e-6f;
      float e = beta * fabsf(covA[j][r] / denom);
      e32[j][r] = e;
      float es = e * 16.f;
      half_t hh = (half_t)es;
      e_h[SQI(n, m)] = hh;
      e_l[SQI(n, m)] = (half_t)(es - (float)hh);
    }
  }

  // ---- phase 5: MLP via MFMA, K-chunked, T14-prefetched ----
  float a1buf[16], a2buf[16];
#define LOAD_A1(jc_)                                                          \
  do {                                                                        \
    _Pragma("unroll") for (int hf_ = 0; hf_ < 2; ++hf_)                       \
      _Pragma("unroll") for (int q_ = 0; q_ < 8; ++q_)                        \
        a1buf[hf_ * 8 + q_] =                                                 \
            A1[(size_t)((w + 4 * hf_) * 8 + q_) * 256 + (jc_) * 64 + lane];   \
  } while (0)
#define LOAD_A2(jc_)                                                          \
  do {                                                                        \
    _Pragma("unroll") for (int hf_ = 0; hf_ < 2; ++hf_)                       \
      _Pragma("unroll") for (int q_ = 0; q_ < 8; ++q_)                        \
        a2buf[hf_ * 8 + q_] =                                                 \
            A2[(size_t)((jc_) * 64 + (w + 4 * hf_) * 8 + q_) * 64 + lane];    \
  } while (0)

  LOAD_A1(0);
  __syncthreads();

  f32x4 adj[4];
#pragma unroll
  for (int j = 0; j < 4; ++j) adj[j] = (f32x4){0.f, 0.f, 0.f, 0.f};

#pragma unroll 1
  for (int jc = 0; jc < 4; ++jc) {
#pragma unroll
    for (int hf = 0; hf < 2; ++hf) {
      int mo = w + 4 * hf;
      int jl = lane;
      half8 hh, hl;
#pragma unroll
      for (int q = 0; q < 8; ++q) {
        float x = a1buf[hf * 8 + q] * 64.f;
        half_t h = (half_t)x;
        hh[q] = h; hl[q] = (half_t)(x - (float)h);
      }
      int ad = jl * 64 + ((mo ^ (jl & 7)) << 3);
      *(half8*)&ab_h[ad] = hh;
      *(half8*)&ab_l[ad] = hl;
    }
    __syncthreads();
    LOAD_A2(jc);

    f32x4 h1[4];
#pragma unroll
    for (int j = 0; j < 4; ++j) h1[j] = (f32x4){0.f, 0.f, 0.f, 0.f};
#pragma unroll
    for (int s = 0; s < 2; ++s) {
      int ra = w * 16 + lr;
      half8 ah = *(const half8*)&e_h[SQI(ra, (s * 4 + ko) * 8)];
      half8 al = *(const half8*)&e_l[SQI(ra, (s * 4 + ko) * 8)];
#pragma unroll
      for (int jt = 0; jt < 4; ++jt) {
        int jl = jt * 16 + lr;
        half8 bh = *(const half8*)&ab_h[SQI(jl, (s * 4 + ko) * 8)];
        half8 bl = *(const half8*)&ab_l[SQI(jl, (s * 4 + ko) * 8)];
        h1[jt] = __builtin_amdgcn_mfma_f32_16x16x32_f16(ah, bh, h1[jt], 0, 0, 0);
        h1[jt] = __builtin_amdgcn_mfma_f32_16x16x32_f16(ah, bl, h1[jt], 0, 0, 0);
        h1[jt] = __builtin_amdgcn_mfma_f32_16x16x32_f16(al, bh, h1[jt], 0, 0, 0);
      }
    }
#pragma unroll
    for (int jt = 0; jt < 4; ++jt) {
#pragma unroll
      for (int r = 0; r < 4; ++r) {
        float x = fmaxf(h1[jt][r], 0.f);
        int n = w * 16 + 4 * ko + r;
        int jl = jt * 16 + lr;
        half_t hh = (half_t)x;
        hid_h[SQI(n, jl)] = hh;
        hid_l[SQI(n, jl)] = (half_t)(x - (float)hh);
      }
    }
    __syncthreads();

#pragma unroll
    for (int hf = 0; hf < 2; ++hf) {
      int ko2 = w + 4 * hf;
      int m = lane;
      half8 hh, hl;
#pragma unroll
      for (int q = 0; q < 8; ++q) {
        float x = a2buf[hf * 8 + q] * 64.f;
        half_t h = (half_t)x;
        hh[q] = h; hl[q] = (half_t)(x - (float)h);
      }
      int ad = m * 64 + ((ko2 ^ (m & 7)) << 3);
      *(half8*)&ab_h[ad] = hh;
      *(half8*)&ab_l[ad] = hl;
    }
    __syncthreads();
    if (jc < 3) LOAD_A1(jc + 1);

#pragma unroll
    for (int s = 0; s < 2; ++s) {
      int ra = w * 16 + lr;
      half8 ah = *(const half8*)&hid_h[SQI(ra, (s * 4 + ko) * 8)];
      half8 al = *(const half8*)&hid_l[SQI(ra, (s * 4 + ko) * 8)];
#pragma unroll
      for (int mt = 0; mt < 4; ++mt) {
        int m = mt * 16 + lr;
        half8 bh = *(const half8*)&ab_h[SQI(m, (s * 4 + ko) * 8)];
        half8 bl = *(const half8*)&ab_l[SQI(m, (s * 4 + ko) * 8)];
        adj[mt] = __builtin_amdgcn_mfma_f32_16x16x32_f16(ah, bh, adj[mt], 0, 0, 0);
        adj[mt] = __builtin_amdgcn_mfma_f32_16x16x32_f16(ah, bl, adj[mt], 0, 0, 0);
        adj[mt] = __builtin_amdgcn_mfma_f32_16x16x32_f16(al, bh, adj[mt], 0, 0, 0);
      }
    }
    __syncthreads();
  }
#undef LOAD_A1
#undef LOAD_A2

  // ---- phase 6: mask + row-softmax, split probs -> at_hl ----
  {
    float p[4][4];
#pragma unroll
    for (int r = 0; r < 4; ++r) {
      float mx = -3.0e38f;
#pragma unroll
      for (int mt = 0; mt < 4; ++mt) {
        float pre = e32[mt][r] + adj[mt][r] * (1.f / 65536.f);
        p[mt][r] = (pre > 0.f) ? e32[mt][r] : -1e12f;
        mx = fmaxf(mx, p[mt][r]);
      }
      mx = fmaxf(mx, __shfl_xor(mx, 1));
      mx = fmaxf(mx, __shfl_xor(mx, 2));
      mx = fmaxf(mx, __shfl_xor(mx, 4));
      mx = fmaxf(mx, __shfl_xor(mx, 8));
      float ssum = 0.f;
#pragma unroll
      for (int mt = 0; mt < 4; ++mt) {
        p[mt][r] = expf(p[mt][r] - mx);
        ssum += p[mt][r];
      }
      ssum += __shfl_xor(ssum, 1);
      ssum += __shfl_xor(ssum, 2);
      ssum += __shfl_xor(ssum, 4);
      ssum += __shfl_xor(ssum, 8);
      float inv = 1.f / ssum;
      int n = w * 16 + 4 * ko + r;
#pragma unroll
      for (int mt = 0; mt < 4; ++mt) {
        float pv = p[mt][r] * inv;
        int m = mt * 16 + lr;
        half_t hh = (half_t)pv;
        at_h[SQI(n, m)] = hh;
        at_l[SQI(n, m)] = (half_t)(pv - (float)hh);
      }
    }
  }

  // ---- phase 7: out = attn @ Wh via MFMA, T14-prefetched chunks ----
  const int fl0 = t & 127;
  const int moB = t >> 7;
  float wbuf[32];
#define LOAD_WT(fc_)                                                          \
  do {                                                                        \
    _Pragma("unroll") for (int i_ = 0; i_ < 4; ++i_) {                        \
      int mo_ = moB + 2 * i_;                                                 \
      _Pragma("unroll") for (int q_ = 0; q_ < 8; ++q_)                        \
        wbuf[i_ * 8 + q_] =                                                   \
            whb[(size_t)(mo_ * 8 + q_) * F_ + (fc_) * 128 + fl0];             \
    }                                                                         \
  } while (0)

  LOAD_WT(0);
#pragma unroll 1
  for (int fc = 0; fc < 4; ++fc) {
    __syncthreads();
#pragma unroll
    for (int i = 0; i < 4; ++i) {
      int mo = moB + 2 * i;
      half8 hh, hl;
#pragma unroll
      for (int q = 0; q < 8; ++q) {
        float x = wbuf[i * 8 + q];
        half_t h = (half_t)x;
        hh[q] = h; hl[q] = (half_t)(x - (float)h);
      }
      int ad = fl0 * 64 + ((mo ^ (fl0 & 7)) << 3);
      *(half8*)&wt_h[ad] = hh;
      *(half8*)&wt_l[ad] = hl;
    }
    __syncthreads();
    if (fc < 3) LOAD_WT(fc + 1);

    half8 aah[2], aal[2];
#pragma unroll
    for (int s = 0; s < 2; ++s) {
      int n = w * 16 + lr;
      aah[s] = *(const half8*)&at_h[SQI(n, (s * 4 + ko) * 8)];
      aal[s] = *(const half8*)&at_l[SQI(n, (s * 4 + ko) * 8)];
    }
#pragma unroll
    for (int ft = 0; ft < 8; ++ft) {
      f32x4 po = (f32x4){0.f, 0.f, 0.f, 0.f};
#pragma unroll
      for (int s = 0; s < 2; ++s) {
        int fl = ft * 16 + lr;
        int ad = fl * 64 + (((((s * 4 + ko)) ^ (fl & 7))) << 3);
        half8 bh = *(const half8*)&wt_h[ad];
        half8 bl = *(const half8*)&wt_l[ad];
        po = __builtin_amdgcn_mfma_f32_16x16x32_f16(aah[s], bh, po, 0, 0, 0);
        po = __builtin_amdgcn_mfma_f32_16x16x32_f16(aah[s], bl, po, 0, 0, 0);
        po = __builtin_amdgcn_mfma_f32_16x16x32_f16(aal[s], bh, po, 0, 0, 0);
      }
      int fg = fc * 128 + ft * 16 + lr;
#pragma unroll
      for (int r = 0; r < 4; ++r) {
        int n = w * 16 + 4 * ko + r;
        out[(size_t)b * N_ * F_ + n * F_ + fg] = po[r];
      }
    }
  }
#undef LOAD_WT
}

extern "C" void kernel_launch(void* const* d_in, const int* in_sizes, int n_in,
                              void* d_out, int out_size, void* d_ws, size_t ws_size,
                              hipStream_t stream) {
  const float* h    = (const float*)d_in[0];
  const float* W    = (const float*)d_in[1];
  const float* beta = (const float*)d_in[2];
  const float* A1   = (const float*)d_in[3];
  const float* A2   = (const float*)d_in[4];
  float* out = (float*)d_out;
  float* Wh  = (float*)d_ws;  // 128 MiB workspace

  half_t* wt_hi = (half_t*)d_out;
  half_t* wt_lo = wt_hi + 512 * 512;

  k_split_w<<<1024, 256, 0, stream>>>(W, wt_hi, wt_lo);
  k_wh<<<2048, 256, 0, stream>>>(h, wt_hi, wt_lo, Wh);
  k_attn<<<B_, 256, 0, stream>>>(Wh, A1, A2, beta, out);
}